// Round 10
// baseline (2324.649 us; speedup 1.0000x reference)
//
#include <hip/hip_runtime.h>
#include <hip/hip_bf16.h>
#include <cstdio>

#define Bn 2
#define Cn 512
#define Sn 256
#define En 512

typedef __attribute__((ext_vector_type(8))) short bf16x8;
typedef __attribute__((ext_vector_type(4))) float f32x4;

// Workspace layout (bytes):
//   [0, 2048)        : mean[512] f32 ; [2048,4096): rstd[512] f32
//   byte 1 MiB       : prod f32 [1024][256][256]                   (256 MiB)
//   byte 1MiB+256MiB : vT bf16 tiled [1024][4 fh][4 kt][128][64]   (256 MiB)
//   + ATh, ATl tiled [8 ft][8 et][64][64] bf16 (512 KiB each)
//   + VT tiled [4 fq][8 et][128][64] bf16 (512 KiB)
//   + XNh, XNl tiled [1024 bc][8 et][256][64] bf16 (256 MiB each)
//   smT (bf16 sm, tiled [1024 bc][2 sh][4 kt][128][64]) ALIASES XNl (dead after kscores).
static constexpr size_t PROD_B = (1ull << 20);
static constexpr size_t V_B    = PROD_B + (256ull << 20);
static constexpr size_t ATH_B  = V_B + (256ull << 20);
static constexpr size_t ATL_B  = ATH_B + (512ull << 10);
static constexpr size_t VT_B   = ATL_B + (512ull << 10);
static constexpr size_t XNH_B  = VT_B + (512ull << 10);
static constexpr size_t XNL_B  = XNH_B + (256ull << 20);
static constexpr size_t WS_BIG = XNL_B + (256ull << 20);
static constexpr size_t SMT_B  = XNL_B;  // alias: XNl dead after kscores

__device__ __forceinline__ unsigned short f2bf(float f) {
  union { __hip_bfloat16 h; unsigned short u; } cv;
  cv.h = __float2bfloat16(f);
  return cv.u;
}
__device__ __forceinline__ float bf2f(unsigned short u) {
  union { unsigned int i; float f; } cv;
  cv.i = ((unsigned int)u) << 16;
  return cv.f;
}
__device__ __forceinline__ void split2(float v, unsigned short& h, unsigned short& l) {
  h = f2bf(v);
  l = f2bf(v - bf2f(h));
}
// MFMA fragment load from a [R][64] swizzled LDS tile: row `row`, k-chunk ks*32+(lane>>4)*8.
__device__ __forceinline__ bf16x8 ldfrag(const unsigned short* arr, int row, int ks, int lane) {
  const int byte = (ks * 64 + ((lane >> 4) << 4)) ^ ((row & 7) << 4);
  return *(const bf16x8*)((const char*)(arr + (size_t)row * 64) + byte);
}
__device__ __forceinline__ f32x4 MFMA(bf16x8 a, bf16x8 b, f32x4 c) {
  return __builtin_amdgcn_mfma_f32_16x16x32_bf16(a, b, c, 0, 0, 0);
}
__device__ __forceinline__ void glds16(const void* g, void* l) {
  __builtin_amdgcn_global_load_lds(
      (const __attribute__((address_space(1))) unsigned int*)g,
      (__attribute__((address_space(3))) unsigned int*)l, 16, 0, 0);
}
// stage nbytes (multiple of 1024) from pre-tiled global (LDS-linear order) into LDS.
__device__ __forceinline__ void stage_tile(const unsigned short* g, unsigned short* l,
                                           int nbytes, int wid, int lane, int nwaves) {
  const char* gb = (const char*)g;
  char* lb = (char*)l;
  for (int j = wid; j < (nbytes >> 10); j += nwaves)
    glds16(gb + j * 1024 + lane * 16, lb + j * 1024);
}

// ---------------- K1: per-channel mean / rstd ----------------
__global__ void k1_stats(const float* __restrict__ x, float* __restrict__ ws) {
  const int c = blockIdx.x, tid = threadIdx.x;
  const float4* p0 = (const float4*)(x + (size_t)c * (Sn * En));
  const float4* p1 = (const float4*)(x + (size_t)(Cn + c) * (Sn * En));
  float s1 = 0.f, s2 = 0.f;
  for (int i = tid; i < (Sn * En / 4); i += 256) {
    float4 a = p0[i], b = p1[i];
    s1 += (a.x + a.y) + (a.z + a.w) + (b.x + b.y) + (b.z + b.w);
    s2 += (a.x * a.x + a.y * a.y) + (a.z * a.z + a.w * a.w) +
          (b.x * b.x + b.y * b.y) + (b.z * b.z + b.w * b.w);
  }
  __shared__ float r1[256], r2[256];
  r1[tid] = s1; r2[tid] = s2;
  __syncthreads();
  for (int off = 128; off > 0; off >>= 1) {
    if (tid < off) { r1[tid] += r1[tid + off]; r2[tid] += r2[tid + off]; }
    __syncthreads();
  }
  if (tid == 0) {
    const float n = (float)(2 * Sn * En);
    float mean = r1[0] / n;
    float var = r2[0] / n - mean * mean;
    ws[c] = mean;
    ws[512 + c] = 1.0f / sqrtf(var + 1e-5f);
  }
}

// ---------------- kA: AT = K·Q^T split hi/lo bf16 (tiled); VT = V^T bf16 (tiled) ------
__global__ void kA(const float* __restrict__ Q, const float* __restrict__ K,
                   const float* __restrict__ V, unsigned short* __restrict__ ATh,
                   unsigned short* __restrict__ ATl, unsigned short* __restrict__ VT) {
  const int f = blockIdx.x, tid = threadIdx.x;
  __shared__ float Kf[512];
  for (int i = tid; i < 512; i += 256) Kf[i] = K[(size_t)f * 512 + i];
  __syncthreads();
  const int fr64 = f & 63;
  const size_t atbase = ((size_t)(f >> 6) * 8) * 4096 + (size_t)fr64 * 64;
  const size_t vtbase = ((size_t)(f >> 7) * 8) * 8192 + (size_t)(f & 127) * 64;
#pragma unroll
  for (int half = 0; half < 2; ++half) {
    const int e = tid + half * 256;
    const float* Qe = Q + (size_t)e * 512;
    float acc = 0.f;
    for (int t = 0; t < 512; t += 4) {
      float4 q = *(const float4*)(Qe + t);
      acc += q.x * Kf[t] + q.y * Kf[t + 1] + q.z * Kf[t + 2] + q.w * Kf[t + 3];
    }
    unsigned short h, l;
    split2(acc, h, l);
    const int et = e >> 6, ec = e & 63;
    const int swa = (ec & 3) | ((ec & 60) ^ ((fr64 & 7) << 3));
    ATh[atbase + (size_t)et * 4096 + swa] = h;
    ATl[atbase + (size_t)et * 4096 + swa] = l;
    const int swv = (ec & 3) | ((ec & 60) ^ ((f & 7) << 3));
    VT[vtbase + (size_t)et * 8192 + swv] = f2bf(V[(size_t)e * 512 + f]);
  }
}

// ---------------- kxn: pre-split xn into tiled+swizzled hi/lo bf16 ----------------
__global__ void kxn(const float* __restrict__ x, const float* __restrict__ ws,
                    unsigned short* __restrict__ XNh, unsigned short* __restrict__ XNl) {
  const int bid = blockIdx.x;  // (bc, half)
  const int bc = bid >> 1, half = bid & 1;
  const int c = bc & 511;
  const float mean = ws[c], rstd = ws[512 + c];
  const float* xb = x + (size_t)bc * 131072 + (size_t)half * 128 * 512;
  const int tid = threadIdx.x;
#pragma unroll 4
  for (int i = 0; i < 64; ++i) {
    const int g = tid + i * 256;       // 128 rows x 128 col-groups
    const int r = g >> 7, c4 = g & 127;
    const float4 xv = *(const float4*)(xb + (size_t)r * 512 + c4 * 4);
    ushort4 hv, lv;
    split2((xv.x - mean) * rstd, hv.x, lv.x);
    split2((xv.y - mean) * rstd, hv.y, lv.y);
    split2((xv.z - mean) * rstd, hv.z, lv.z);
    split2((xv.w - mean) * rstd, hv.w, lv.w);
    const int et = c4 >> 4, colt4 = c4 & 15;
    const int row = half * 128 + r;
    const size_t idx = ((size_t)(bc * 8 + et) * 256 + row) * 64 +
                       ((colt4 * 4) ^ ((row & 7) << 3));
    *(ushort4*)&XNh[idx] = hv;
    *(ushort4*)&XNl[idx] = lv;
  }
}

// ---------------- kv_proj: vT[f][t] = sum_e VT[f][e]*xn[t][e]  (dbuf pipeline) -------
__launch_bounds__(256)
__global__ void kv_proj(const unsigned short* __restrict__ VT,
                        const unsigned short* __restrict__ XNh_g,
                        unsigned short* __restrict__ vT_out) {
  __shared__ unsigned short BUF[2][16384];  // each: [VT 8192][XN 8192] = 32 KiB
  const int bid = blockIdx.x;
  const int L = (bid & 7) * 1024 + (bid >> 3);  // chunked XCD swizzle
  const int bc = L >> 3;
  const int fq = (L >> 1) & 3;
  const int th = L & 1;
  const int f0 = fq * 128, t0 = th * 128;
  const int tid = threadIdx.x, w = tid >> 6, lane = tid & 63;

  f32x4 acc[2][8];
#pragma unroll
  for (int i = 0; i < 2; ++i)
#pragma unroll
    for (int j = 0; j < 8; ++j) acc[i][j] = (f32x4){0.f, 0.f, 0.f, 0.f};

  stage_tile(VT + ((size_t)fq * 8 + 0) * 8192, &BUF[0][0], 16384, w, lane, 4);
  stage_tile(XNh_g + ((size_t)(bc * 8 + 0) * 256 + t0) * 64, &BUF[0][8192], 16384, w, lane, 4);
  __syncthreads();
#pragma unroll 1
  for (int et = 0; et < 8; ++et) {
    if (et < 7) {
      const int b = (et + 1) & 1;
      stage_tile(VT + ((size_t)fq * 8 + et + 1) * 8192, &BUF[b][0], 16384, w, lane, 4);
      stage_tile(XNh_g + ((size_t)(bc * 8 + et + 1) * 256 + t0) * 64, &BUF[b][8192],
                 16384, w, lane, 4);
    }
    const unsigned short* cb = &BUF[et & 1][0];
#pragma unroll
    for (int ks = 0; ks < 2; ++ks) {
      bf16x8 a0 = ldfrag(cb, w * 32 + (lane & 15), ks, lane);
      bf16x8 a1 = ldfrag(cb, w * 32 + 16 + (lane & 15), ks, lane);
#pragma unroll
      for (int ct = 0; ct < 8; ++ct) {
        bf16x8 b = ldfrag(cb + 8192, ct * 16 + (lane & 15), ks, lane);
        acc[0][ct] = MFMA(a0, b, acc[0][ct]);
        acc[1][ct] = MFMA(a1, b, acc[1][ct]);
      }
    }
    __syncthreads();
  }
#pragma unroll
  for (int rt = 0; rt < 2; ++rt)
#pragma unroll
    for (int ct = 0; ct < 8; ++ct)
#pragma unroll
      for (int r = 0; r < 4; ++r) {
        const int f = f0 + w * 32 + rt * 16 + (lane >> 4) * 4 + r;
        const int t = t0 + ct * 16 + (lane & 15);
        const size_t idx = (((size_t)bc * 4 + (f >> 7)) * 4 + (t >> 6)) * 8192 +
                           (size_t)(f & 127) * 64 +
                           ((t & 3) | ((t & 60) ^ ((f & 7) << 3)));
        vT_out[idx] = f2bf(acc[rt][ct][r]);
      }
}

// ---------------- kscores: z = (xn·A)·xn^T / sqrt(E), 3-MFMA split ----------------
// grid 2048: (bc, s-half), 8 waves, wave owns 16 s-rows. ONE barrier per ft (9/block):
//  - ph1: BOTH operands global->reg. A (xn s-rows) wave-private (r8-proven); B (AT)
//    is 1 MiB total, read by all 2048 blocks -> L2/L3-resident; each (ft,et) 16 KiB
//    tile is L1-resident while the 8 waves sweep it. No staging, no barriers.
//  - ph2: XN t-slab (64 KiB) double-buffered in LDS, staged one full ft (~6K cyc)
//    before its drain -> hidden. Y per-wave scratch 2 KiB (two 32-f halves),
//    row-XOR swizzled (fixes r9's 8-way conflict).
// LDS = 128K XNS dbuf + 16K YS = 147456 B (r5-proven size). Waves free-run between
// the per-ft barriers (m114 overlap); T5 setprio around ph2 MFMA cluster.
__launch_bounds__(512)
__global__ void kscores(const unsigned short* __restrict__ ATh_g,
                        const unsigned short* __restrict__ ATl_g,
                        const unsigned short* __restrict__ XNh_g,
                        const unsigned short* __restrict__ XNl_g,
                        float* __restrict__ prod) {
  __shared__ unsigned short XNS[2][32768];  // per buf: [h 16384][l 16384] = 64 KiB
  __shared__ unsigned short YS[8][1024];    // per wave: [h 512][l 512] = 16r x 32f
  const int bid = blockIdx.x;
  const int L = (bid & 7) * 256 + (bid >> 3);  // chunked XCD swizzle: s-halves co-XCD
  const int bc = L >> 1, half = L & 1;
  float* prodc = prod + (size_t)bc * 65536 + (size_t)half * 128 * 256;
  const int tid = threadIdx.x, w = tid >> 6, lane = tid & 63;
  const int lr = lane & 15, lk = lane >> 4;

  // ph1 A-frag global addressing (XN tiled+swizzled; XOR folded into address)
  const int arow = half * 128 + w * 16 + lr;
  const unsigned short* xnh_row = XNh_g + ((size_t)bc * 8 * 256 + arow) * 64;
  const unsigned short* xnl_row = XNl_g + ((size_t)bc * 8 * 256 + arow) * 64;
  const int ac0 = (lk * 8) ^ ((arow & 7) << 3);       // ks=0 (ushort units)
  const int ac1 = (32 + lk * 8) ^ ((arow & 7) << 3);  // ks=1
  const int brswz = (lr & 7) << 3;                    // AT row&7 == lr&7

  f32x4 accz[16];
#pragma unroll
  for (int i = 0; i < 16; ++i) accz[i] = (f32x4){0.f, 0.f, 0.f, 0.f};
  f32x4 accy[4];
  unsigned short* const ys = &YS[w][0];

  auto stXNS = [&](int ft, int p) {
    stage_tile(XNh_g + (size_t)(bc * 8 + ft) * 16384, &XNS[p][0], 32768, w, lane, 8);
    stage_tile(XNl_g + (size_t)(bc * 8 + ft) * 16384, &XNS[p][16384], 32768, w, lane, 8);
  };

  stXNS(0, 0);
  __syncthreads();

#pragma unroll 1
  for (int ft = 0; ft < 8; ++ft) {
    if (ft < 7) stXNS(ft + 1, (ft + 1) & 1);  // hidden: drained by end-of-ft barrier
#pragma unroll
    for (int i = 0; i < 4; ++i) accy[i] = (f32x4){0.f, 0.f, 0.f, 0.f};

    // ---- ph1: accy += xn_srows · AT(ft)^T over all 512 e; A and B global->reg ----
#pragma unroll 2
    for (int et = 0; et < 8; ++et) {
      const unsigned short* ATh_t = ATh_g + ((size_t)ft * 8 + et) * 4096;
      const unsigned short* ATl_t = ATl_g + ((size_t)ft * 8 + et) * 4096;
#pragma unroll
      for (int ks = 0; ks < 2; ++ks) {
        const int ac = ks ? ac1 : ac0;
        const bf16x8 ah = *(const bf16x8*)(xnh_row + (size_t)et * 16384 + ac);
        const bf16x8 al = *(const bf16x8*)(xnl_row + (size_t)et * 16384 + ac);
        const int bko = (ks * 32 + lk * 8) ^ brswz;
#pragma unroll
        for (int fc = 0; fc < 4; ++fc) {
          const int bidx = (fc * 16 + lr) * 64 + bko;
          const bf16x8 bh = *(const bf16x8*)(ATh_t + bidx);
          const bf16x8 bl = *(const bf16x8*)(ATl_t + bidx);
          accy[fc] = MFMA(ah, bh, accy[fc]);
          accy[fc] = MFMA(ah, bl, accy[fc]);
          accy[fc] = MFMA(al, bh, accy[fc]);
        }
      }
    }

    // ---- ph2: accz += y · xn_t^T, two 32-f halves; B from XNS dbuf, y via scratch ----
    const unsigned short* XH = &XNS[ft & 1][0];
    const unsigned short* XL = &XNS[ft & 1][16384];
#pragma unroll
    for (int fh2 = 0; fh2 < 2; ++fh2) {
      // y half -> per-wave scratch (row-XOR swizzle on byte bits 4-5)
#pragma unroll
      for (int fc2 = 0; fc2 < 2; ++fc2)
#pragma unroll
        for (int r = 0; r < 4; ++r) {
          unsigned short h, l;
          split2(accy[fh2 * 2 + fc2][r], h, l);
          const int row = lk * 4 + r, col = fc2 * 16 + lr;
          const int idx = row * 32 + ((col & 7) | ((col & 24) ^ ((row & 3) << 3)));
          ys[idx] = h;
          ys[512 + idx] = l;
        }
      // same-wave RAW through LDS: compiler inserts lgkmcnt waits
      const int yoff = lr * 32 + ((lk * 8) ^ ((lr & 3) << 3));
      const bf16x8 yh = *(const bf16x8*)(ys + yoff);
      const bf16x8 yl = *(const bf16x8*)(ys + 512 + yoff);
      __builtin_amdgcn_s_setprio(1);
#pragma unroll
      for (int ct = 0; ct < 16; ++ct) {
        const bf16x8 bh = ldfrag(XH, ct * 16 + lr, fh2, lane);
        const bf16x8 bl = ldfrag(XL, ct * 16 + lr, fh2, lane);
        accz[ct] = MFMA(yh, bh, accz[ct]);
        accz[ct] = MFMA(yh, bl, accz[ct]);
        accz[ct] = MFMA(yl, bh, accz[ct]);
      }
      __builtin_amdgcn_s_setprio(0);
    }
    __syncthreads();  // drains next-ft stage; frees buf[(ft+1)&1] readers
  }

  const float scale = 0.044194173824159216f;  // 1/sqrt(512)
#pragma unroll
  for (int ct = 0; ct < 16; ++ct)
#pragma unroll
    for (int r = 0; r < 4; ++r) {
      const int row = w * 16 + lk * 4 + r;
      prodc[(size_t)row * 256 + ct * 16 + lr] = accz[ct][r] * scale;
    }
}

// ---------------- K3: cross-channel softmax -> bf16 sm in k4-tiled layout ----------
__launch_bounds__(512)
__global__ void k3_softmax(const float* __restrict__ prodf, unsigned short* __restrict__ smT) {
  const int bid = blockIdx.x;  // b*256 + s
  const int b = bid >> 8, s = bid & 255;
  const int tid = threadIdx.x;
  const int t = tid & 255, ch = tid >> 8;
  const float* __restrict__ p =
      prodf + (size_t)b * (512ull * 65536) + (size_t)s * 256 + t + (size_t)ch * 256 * 65536;
  float m = -3.4e38f, sum = 0.f;
#pragma unroll 4
  for (int cc = 0; cc < 256; ++cc) {
    const float v = p[(size_t)cc * 65536];
    if (v > m) { sum *= __expf(m - v); m = v; }
    sum += __expf(v - m);
  }
  __shared__ float Ms[2][256], Ss[2][256];
  Ms[ch][t] = m; Ss[ch][t] = sum;
  __syncthreads();
  const float mo = Ms[ch ^ 1][t], so = Ss[ch ^ 1][t];
  const float mm = fmaxf(m, mo);
  const float inv = 1.0f / (sum * __expf(m - mm) + so * __expf(mo - mm));
  const int sh = s >> 7, r = s & 127, kt = t >> 6, col = t & 63;
  const int cidx = r * 64 + ((col & 3) | ((col & 60) ^ ((r & 7) << 3)));
  const size_t tbase = ((size_t)b * 512 + ch * 256) * 2 + sh;
#pragma unroll 4
  for (int cc = 0; cc < 256; ++cc) {
    const float ev = __expf(p[(size_t)cc * 65536] - mm) * inv;
    smT[((tbase + (size_t)cc * 2) * 4 + kt) * 8192 + cidx] = f2bf(ev);
  }
}

// ---------------- K4: out = sm·v + xn  (bf16 MFMA; residual from XNh bf16) ----------
__launch_bounds__(256)
__global__ void k4_pv(const unsigned short* __restrict__ XNh_g,
                      const unsigned short* __restrict__ vT,
                      const unsigned short* __restrict__ smT,
                      float* __restrict__ out) {
  __shared__ unsigned short BUF[2][16384];  // each: [SM 8192][VT 8192] = 32 KiB
  const int bid = blockIdx.x;
  const int L = (bid & 7) * 1024 + (bid >> 3);  // chunked XCD swizzle
  const int bc = L >> 3;
  const int sh = (L >> 2) & 1;
  const int fh = L & 3;
  const int s0 = sh * 128, f0 = fh * 128;
  const int tid = threadIdx.x, w = tid >> 6, lane = tid & 63;

  f32x4 acc[2][8];
#pragma unroll
  for (int i = 0; i < 2; ++i)
#pragma unroll
    for (int j = 0; j < 8; ++j) acc[i][j] = (f32x4){0.f, 0.f, 0.f, 0.f};

  stage_tile(smT + (((size_t)bc * 2 + sh) * 4 + 0) * 8192, &BUF[0][0], 16384, w, lane, 4);
  stage_tile(vT + (((size_t)bc * 4 + fh) * 4 + 0) * 8192, &BUF[0][8192], 16384, w, lane, 4);
  __syncthreads();
#pragma unroll 1
  for (int kt = 0; kt < 4; ++kt) {
    if (kt < 3) {
      const int b = (kt + 1) & 1;
      stage_tile(smT + (((size_t)bc * 2 + sh) * 4 + kt + 1) * 8192, &BUF[b][0],
                 16384, w, lane, 4);
      stage_tile(vT + (((size_t)bc * 4 + fh) * 4 + kt + 1) * 8192, &BUF[b][8192],
                 16384, w, lane, 4);
    }
    const unsigned short* cb = &BUF[kt & 1][0];
#pragma unroll
    for (int ks = 0; ks < 2; ++ks) {
      bf16x8 a0 = ldfrag(cb, w * 32 + (lane & 15), ks, lane);
      bf16x8 a1 = ldfrag(cb, w * 32 + 16 + (lane & 15), ks, lane);
#pragma unroll
      for (int ct = 0; ct < 8; ++ct) {
        bf16x8 b = ldfrag(cb + 8192, ct * 16 + (lane & 15), ks, lane);
        acc[0][ct] = MFMA(a0, b, acc[0][ct]);
        acc[1][ct] = MFMA(a1, b, acc[1][ct]);
      }
    }
    __syncthreads();
  }
  const int lr = lane & 15, lk = lane >> 4;
#pragma unroll
  for (int rt = 0; rt < 2; ++rt)
#pragma unroll
    for (int ct = 0; ct < 8; ++ct)
#pragma unroll
      for (int r = 0; r < 4; ++r) {
        const int srow = s0 + w * 32 + rt * 16 + lk * 4 + r;
        const int fcol = f0 + ct * 16 + lr;
        const int et = fcol >> 6, col = fcol & 63;
        const unsigned short xh = XNh_g[((size_t)(bc * 8 + et) * 256 + srow) * 64 +
                                        ((col & 3) | ((col & 60) ^ ((srow & 7) << 3)))];
        const size_t oi = (size_t)bc * 131072 + (size_t)srow * 512 + fcol;
        out[oi] = acc[rt][ct][r] + bf2f(xh);
      }
}

extern "C" void kernel_launch(void* const* d_in, const int* in_sizes, int n_in,
                              void* d_out, int out_size, void* d_ws, size_t ws_size,
                              hipStream_t stream) {
  const float* x = (const float*)d_in[0];
  const float* Q = (const float*)d_in[1];
  const float* K = (const float*)d_in[2];
  const float* V = (const float*)d_in[3];
  float* out = (float*)d_out;
  float* ws = (float*)d_ws;
  float* prodf = (float*)((char*)d_ws + PROD_B);
  unsigned short* vT   = (unsigned short*)((char*)d_ws + V_B);
  unsigned short* ATh  = (unsigned short*)((char*)d_ws + ATH_B);
  unsigned short* ATl  = (unsigned short*)((char*)d_ws + ATL_B);
  unsigned short* VTm  = (unsigned short*)((char*)d_ws + VT_B);
  unsigned short* XNh  = (unsigned short*)((char*)d_ws + XNH_B);
  unsigned short* XNl  = (unsigned short*)((char*)d_ws + XNL_B);
  unsigned short* smT  = (unsigned short*)((char*)d_ws + SMT_B);
  if (ws_size < WS_BIG) {
    fprintf(stderr, "kernel_launch: ws_size %zu < needed %zu — expect corruption\n",
            ws_size, WS_BIG);
  }
  k1_stats<<<dim3(512), dim3(256), 0, stream>>>(x, ws);
  kA<<<dim3(512), dim3(256), 0, stream>>>(Q, K, V, ATh, ATl, VTm);
  kxn<<<dim3(2048), dim3(256), 0, stream>>>(x, ws, XNh, XNl);
  kv_proj<<<dim3(8192), dim3(256), 0, stream>>>(VTm, XNh, vT);
  kscores<<<dim3(2048), dim3(512), 0, stream>>>(ATh, ATl, XNh, XNl, prodf);
  k3_softmax<<<dim3(512), dim3(512), 0, stream>>>(prodf, smT);
  k4_pv<<<dim3(8192), dim3(256), 0, stream>>>(XNh, vT, smT, out);
}

// Round 11
// 1879.800 us; speedup vs baseline: 1.2366x; 1.2366x over previous
//
#include <hip/hip_runtime.h>
#include <hip/hip_bf16.h>
#include <cstdio>

#define Bn 2
#define Cn 512
#define Sn 256
#define En 512

typedef __attribute__((ext_vector_type(8))) short bf16x8;
typedef __attribute__((ext_vector_type(4))) float f32x4;

// Workspace layout (bytes):
//   [0, 2048)        : mean[512] f32 ; [2048,4096): rstd[512] f32
//   byte 1 MiB       : prod f32 [1024][256][256]                   (256 MiB)
//   byte 1MiB+256MiB : vT bf16 tiled [1024][4 fh][4 kt][128][64]   (256 MiB)
//   + ATh, ATl tiled [8 ft][8 et][64][64] bf16 (512 KiB each)
//   + VT tiled [4 fq][8 et][128][64] bf16 (512 KiB)
//   + XNh, XNl tiled [1024 bc][8 et][256][64] bf16 (256 MiB each)
//   smT (bf16 sm, tiled [1024 bc][2 sh][4 kt][128][64]) ALIASES XNl (dead after kscores).
static constexpr size_t PROD_B = (1ull << 20);
static constexpr size_t V_B    = PROD_B + (256ull << 20);
static constexpr size_t ATH_B  = V_B + (256ull << 20);
static constexpr size_t ATL_B  = ATH_B + (512ull << 10);
static constexpr size_t VT_B   = ATL_B + (512ull << 10);
static constexpr size_t XNH_B  = VT_B + (512ull << 10);
static constexpr size_t XNL_B  = XNH_B + (256ull << 20);
static constexpr size_t WS_BIG = XNL_B + (256ull << 20);
static constexpr size_t SMT_B  = XNL_B;  // alias: XNl dead after kscores

__device__ __forceinline__ unsigned short f2bf(float f) {
  union { __hip_bfloat16 h; unsigned short u; } cv;
  cv.h = __float2bfloat16(f);
  return cv.u;
}
__device__ __forceinline__ float bf2f(unsigned short u) {
  union { unsigned int i; float f; } cv;
  cv.i = ((unsigned int)u) << 16;
  return cv.f;
}
__device__ __forceinline__ void split2(float v, unsigned short& h, unsigned short& l) {
  h = f2bf(v);
  l = f2bf(v - bf2f(h));
}
// swizzled ushort index for element (row, col) in a [R][64] tile (byte ^= (row&7)<<4).
__device__ __forceinline__ int swzc(int row, int col) {
  return row * 64 + ((col & 3) | ((col & 60) ^ ((row & 7) << 3)));
}
// MFMA fragment load from a [R][64] swizzled LDS tile: row `row`, k-chunk ks*32+(lane>>4)*8.
__device__ __forceinline__ bf16x8 ldfrag(const unsigned short* arr, int row, int ks, int lane) {
  const int byte = (ks * 64 + ((lane >> 4) << 4)) ^ ((row & 7) << 4);
  return *(const bf16x8*)((const char*)(arr + (size_t)row * 64) + byte);
}
__device__ __forceinline__ f32x4 MFMA(bf16x8 a, bf16x8 b, f32x4 c) {
  return __builtin_amdgcn_mfma_f32_16x16x32_bf16(a, b, c, 0, 0, 0);
}
__device__ __forceinline__ void glds16(const void* g, void* l) {
  __builtin_amdgcn_global_load_lds(
      (const __attribute__((address_space(1))) unsigned int*)g,
      (__attribute__((address_space(3))) unsigned int*)l, 16, 0, 0);
}
// stage nbytes (multiple of 1024) from pre-tiled global (LDS-linear order) into LDS.
__device__ __forceinline__ void stage_tile(const unsigned short* g, unsigned short* l,
                                           int nbytes, int wid, int lane, int nwaves) {
  const char* gb = (const char*)g;
  char* lb = (char*)l;
  for (int j = wid; j < (nbytes >> 10); j += nwaves)
    glds16(gb + j * 1024 + lane * 16, lb + j * 1024);
}

// ---------------- K1: per-channel mean / rstd ----------------
__global__ void k1_stats(const float* __restrict__ x, float* __restrict__ ws) {
  const int c = blockIdx.x, tid = threadIdx.x;
  const float4* p0 = (const float4*)(x + (size_t)c * (Sn * En));
  const float4* p1 = (const float4*)(x + (size_t)(Cn + c) * (Sn * En));
  float s1 = 0.f, s2 = 0.f;
  for (int i = tid; i < (Sn * En / 4); i += 256) {
    float4 a = p0[i], b = p1[i];
    s1 += (a.x + a.y) + (a.z + a.w) + (b.x + b.y) + (b.z + b.w);
    s2 += (a.x * a.x + a.y * a.y) + (a.z * a.z + a.w * a.w) +
          (b.x * b.x + b.y * b.y) + (b.z * b.z + b.w * b.w);
  }
  __shared__ float r1[256], r2[256];
  r1[tid] = s1; r2[tid] = s2;
  __syncthreads();
  for (int off = 128; off > 0; off >>= 1) {
    if (tid < off) { r1[tid] += r1[tid + off]; r2[tid] += r2[tid + off]; }
    __syncthreads();
  }
  if (tid == 0) {
    const float n = (float)(2 * Sn * En);
    float mean = r1[0] / n;
    float var = r2[0] / n - mean * mean;
    ws[c] = mean;
    ws[512 + c] = 1.0f / sqrtf(var + 1e-5f);
  }
}

// ---------------- kA: AT = K·Q^T split hi/lo bf16 (tiled); VT = V^T bf16 (tiled) ------
__global__ void kA(const float* __restrict__ Q, const float* __restrict__ K,
                   const float* __restrict__ V, unsigned short* __restrict__ ATh,
                   unsigned short* __restrict__ ATl, unsigned short* __restrict__ VT) {
  const int f = blockIdx.x, tid = threadIdx.x;
  __shared__ float Kf[512];
  for (int i = tid; i < 512; i += 256) Kf[i] = K[(size_t)f * 512 + i];
  __syncthreads();
  const int fr64 = f & 63;
  const size_t atbase = ((size_t)(f >> 6) * 8) * 4096 + (size_t)fr64 * 64;
  const size_t vtbase = ((size_t)(f >> 7) * 8) * 8192 + (size_t)(f & 127) * 64;
#pragma unroll
  for (int half = 0; half < 2; ++half) {
    const int e = tid + half * 256;
    const float* Qe = Q + (size_t)e * 512;
    float acc = 0.f;
    for (int t = 0; t < 512; t += 4) {
      float4 q = *(const float4*)(Qe + t);
      acc += q.x * Kf[t] + q.y * Kf[t + 1] + q.z * Kf[t + 2] + q.w * Kf[t + 3];
    }
    unsigned short h, l;
    split2(acc, h, l);
    const int et = e >> 6, ec = e & 63;
    const int swa = (ec & 3) | ((ec & 60) ^ ((fr64 & 7) << 3));
    ATh[atbase + (size_t)et * 4096 + swa] = h;
    ATl[atbase + (size_t)et * 4096 + swa] = l;
    const int swv = (ec & 3) | ((ec & 60) ^ ((f & 7) << 3));
    VT[vtbase + (size_t)et * 8192 + swv] = f2bf(V[(size_t)e * 512 + f]);
  }
}

// ---------------- kxn: pre-split xn into tiled+swizzled hi/lo bf16 ----------------
__global__ void kxn(const float* __restrict__ x, const float* __restrict__ ws,
                    unsigned short* __restrict__ XNh, unsigned short* __restrict__ XNl) {
  const int bid = blockIdx.x;  // (bc, half)
  const int bc = bid >> 1, half = bid & 1;
  const int c = bc & 511;
  const float mean = ws[c], rstd = ws[512 + c];
  const float* xb = x + (size_t)bc * 131072 + (size_t)half * 128 * 512;
  const int tid = threadIdx.x;
#pragma unroll 4
  for (int i = 0; i < 64; ++i) {
    const int g = tid + i * 256;       // 128 rows x 128 col-groups
    const int r = g >> 7, c4 = g & 127;
    const float4 xv = *(const float4*)(xb + (size_t)r * 512 + c4 * 4);
    ushort4 hv, lv;
    split2((xv.x - mean) * rstd, hv.x, lv.x);
    split2((xv.y - mean) * rstd, hv.y, lv.y);
    split2((xv.z - mean) * rstd, hv.z, lv.z);
    split2((xv.w - mean) * rstd, hv.w, lv.w);
    const int et = c4 >> 4, colt4 = c4 & 15;
    const int row = half * 128 + r;
    const size_t idx = ((size_t)(bc * 8 + et) * 256 + row) * 64 +
                       ((colt4 * 4) ^ ((row & 7) << 3));
    *(ushort4*)&XNh[idx] = hv;
    *(ushort4*)&XNl[idx] = lv;
  }
}

// ---------------- kv_proj: vT[f][t] = sum_e VT[f][e]*xn[t][e]  (dbuf pipeline) -------
__launch_bounds__(256)
__global__ void kv_proj(const unsigned short* __restrict__ VT,
                        const unsigned short* __restrict__ XNh_g,
                        unsigned short* __restrict__ vT_out) {
  __shared__ unsigned short BUF[2][16384];  // each: [VT 8192][XN 8192] = 32 KiB
  const int bid = blockIdx.x;
  const int L = (bid & 7) * 1024 + (bid >> 3);  // chunked XCD swizzle
  const int bc = L >> 3;
  const int fq = (L >> 1) & 3;
  const int th = L & 1;
  const int f0 = fq * 128, t0 = th * 128;
  const int tid = threadIdx.x, w = tid >> 6, lane = tid & 63;

  f32x4 acc[2][8];
#pragma unroll
  for (int i = 0; i < 2; ++i)
#pragma unroll
    for (int j = 0; j < 8; ++j) acc[i][j] = (f32x4){0.f, 0.f, 0.f, 0.f};

  stage_tile(VT + ((size_t)fq * 8 + 0) * 8192, &BUF[0][0], 16384, w, lane, 4);
  stage_tile(XNh_g + ((size_t)(bc * 8 + 0) * 256 + t0) * 64, &BUF[0][8192], 16384, w, lane, 4);
  __syncthreads();
#pragma unroll 1
  for (int et = 0; et < 8; ++et) {
    if (et < 7) {
      const int b = (et + 1) & 1;
      stage_tile(VT + ((size_t)fq * 8 + et + 1) * 8192, &BUF[b][0], 16384, w, lane, 4);
      stage_tile(XNh_g + ((size_t)(bc * 8 + et + 1) * 256 + t0) * 64, &BUF[b][8192],
                 16384, w, lane, 4);
    }
    const unsigned short* cb = &BUF[et & 1][0];
#pragma unroll
    for (int ks = 0; ks < 2; ++ks) {
      bf16x8 a0 = ldfrag(cb, w * 32 + (lane & 15), ks, lane);
      bf16x8 a1 = ldfrag(cb, w * 32 + 16 + (lane & 15), ks, lane);
#pragma unroll
      for (int ct = 0; ct < 8; ++ct) {
        bf16x8 b = ldfrag(cb + 8192, ct * 16 + (lane & 15), ks, lane);
        acc[0][ct] = MFMA(a0, b, acc[0][ct]);
        acc[1][ct] = MFMA(a1, b, acc[1][ct]);
      }
    }
    __syncthreads();
  }
#pragma unroll
  for (int rt = 0; rt < 2; ++rt)
#pragma unroll
    for (int ct = 0; ct < 8; ++ct)
#pragma unroll
      for (int r = 0; r < 4; ++r) {
        const int f = f0 + w * 32 + rt * 16 + (lane >> 4) * 4 + r;
        const int t = t0 + ct * 16 + (lane & 15);
        const size_t idx = (((size_t)bc * 4 + (f >> 7)) * 4 + (t >> 6)) * 8192 +
                           (size_t)(f & 127) * 64 +
                           ((t & 3) | ((t & 60) ^ ((f & 7) << 3)));
        vT_out[idx] = f2bf(acc[rt][ct][r]);
      }
}

// ---------------- kscores: z = (xn·A)·xn^T / sqrt(E), 3-MFMA split ----------------
// grid 2048: (bc, s-half), 8 waves, wave owns 16 s-rows. r8 structure with 2x coarser
// phases: 32 KiB stage slots {2 AT et-tiles (h+l)} / {XN t-half (h+l)}, 48 MFMA per
// phase, 6 barriers/ft (48 total vs r8's 96). ph1 A-side wave-private global->reg
// (12 MFMA per load-pair); ALL B-operands via LDS ds_read (r10 showed global-B loses).
// LDS = 2x32K STG + 16K YS = 80 KiB. LB(512,2) = VGPR<=128 (r3/r7 empirical mapping).
__launch_bounds__(512, 2)
__global__ void kscores(const unsigned short* __restrict__ ATh_g,
                        const unsigned short* __restrict__ ATl_g,
                        const unsigned short* __restrict__ XNh_g,
                        const unsigned short* __restrict__ XNl_g,
                        float* __restrict__ prod) {
  __shared__ unsigned short STG[2][16384];  // 32 KiB slots: [h 8192][l 8192] ushorts
  __shared__ unsigned short YS[8][2048];    // per-wave y scratch: [h 1024][l 1024]
  const int bid = blockIdx.x;
  const int L = (bid & 7) * 256 + (bid >> 3);  // chunked XCD swizzle: s-halves co-XCD
  const int bc = L >> 1, half = L & 1;
  float* prodc = prod + (size_t)bc * 65536 + (size_t)half * 128 * 256;
  const int tid = threadIdx.x, w = tid >> 6, lane = tid & 63;
  const int lr = lane & 15, lk = lane >> 4;

  // ph1 A-frag global addressing (XN stored tiled+swizzled; XOR folded into address)
  const int arow = half * 128 + w * 16 + lr;
  const unsigned short* xnh_row = XNh_g + ((size_t)bc * 8 * 256 + arow) * 64;
  const unsigned short* xnl_row = XNl_g + ((size_t)bc * 8 * 256 + arow) * 64;
  const int ac0 = (lk * 8) ^ ((arow & 7) << 3);       // ks=0 col offset (ushorts)
  const int ac1 = (32 + lk * 8) ^ ((arow & 7) << 3);  // ks=1

  f32x4 accz[16];
#pragma unroll
  for (int i = 0; i < 16; ++i) accz[i] = (f32x4){0.f, 0.f, 0.f, 0.f};
  f32x4 accy[4];
  unsigned short* const ys = &YS[w][0];

  // stage TWO consecutive AT et-tiles (contiguous in the tiled layout): 16K h + 16K l
  auto stAT2 = [&](int ftx, int et2, int p) {
    stage_tile(ATh_g + ((size_t)ftx * 8 + et2) * 4096, STG[p], 16384, w, lane, 8);
    stage_tile(ATl_g + ((size_t)ftx * 8 + et2) * 4096, STG[p] + 8192, 16384, w, lane, 8);
  };
  // stage XN t-half (128 rows x 64 e): 16K h + 16K l
  auto stXT2 = [&](int ftx, int th, int p) {
    stage_tile(XNh_g + ((size_t)(bc * 8 + ftx) * 256 + th * 128) * 64, STG[p],
               16384, w, lane, 8);
    stage_tile(XNl_g + ((size_t)(bc * 8 + ftx) * 256 + th * 128) * 64, STG[p] + 8192,
               16384, w, lane, 8);
  };
  // ph1 over an et-pair: accy += xn_srows(et)·AT^T ; A global->reg, B from slot p
  auto ph1pair = [&](int et2, int p) {
    __builtin_amdgcn_s_setprio(1);
#pragma unroll
    for (int e2 = 0; e2 < 2; ++e2) {
      const unsigned short* Bh = STG[p] + e2 * 4096;
      const unsigned short* Bl = STG[p] + 8192 + e2 * 4096;
      const size_t abase = (size_t)(et2 + e2) * 16384;
#pragma unroll
      for (int ks = 0; ks < 2; ++ks) {
        const int ac = ks ? ac1 : ac0;
        const bf16x8 ah = *(const bf16x8*)(xnh_row + abase + ac);
        const bf16x8 al = *(const bf16x8*)(xnl_row + abase + ac);
#pragma unroll
        for (int fc = 0; fc < 4; ++fc) {
          bf16x8 bh = ldfrag(Bh, fc * 16 + lr, ks, lane);
          bf16x8 bl = ldfrag(Bl, fc * 16 + lr, ks, lane);
          accy[fc] = MFMA(ah, bh, accy[fc]);
          accy[fc] = MFMA(ah, bl, accy[fc]);
          accy[fc] = MFMA(al, bh, accy[fc]);
        }
      }
    }
    __builtin_amdgcn_s_setprio(0);
  };
  // ph2 over a t-half (128 rows in slot p): accz[z0..z0+7] += y·xn_t^T
  auto ph2half = [&](int z0, int p) {
    __builtin_amdgcn_s_setprio(1);
#pragma unroll
    for (int ks = 0; ks < 2; ++ks) {
      bf16x8 yh = ldfrag(ys, lr, ks, lane);
      bf16x8 yl = ldfrag(ys + 1024, lr, ks, lane);
#pragma unroll
      for (int j = 0; j < 8; ++j) {
        bf16x8 bh = ldfrag(STG[p], j * 16 + lr, ks, lane);
        bf16x8 bl = ldfrag(STG[p] + 8192, j * 16 + lr, ks, lane);
        accz[z0 + j] = MFMA(yh, bh, accz[z0 + j]);
        accz[z0 + j] = MFMA(yh, bl, accz[z0 + j]);
        accz[z0 + j] = MFMA(yl, bh, accz[z0 + j]);
      }
    }
    __builtin_amdgcn_s_setprio(0);
  };
  auto ywrite = [&]() {
#pragma unroll
    for (int fc = 0; fc < 4; ++fc)
#pragma unroll
      for (int r = 0; r < 4; ++r) {
        const int row = lk * 4 + r;
        const int col = fc * 16 + lr;
        unsigned short h, l;
        split2(accy[fc][r], h, l);
        const int idx = swzc(row, col);
        ys[idx] = h;
        ys[1024 + idx] = l;
      }
  };

  stAT2(0, 0, 0);
  __syncthreads();

#pragma unroll 1
  for (int ft = 0; ft < 8; ++ft) {
#pragma unroll
    for (int i = 0; i < 4; ++i) accy[i] = (f32x4){0.f, 0.f, 0.f, 0.f};
    stAT2(ft, 2, 1);                 ph1pair(0, 0); __syncthreads();
    stAT2(ft, 4, 0);                 ph1pair(2, 1); __syncthreads();
    stAT2(ft, 6, 1);                 ph1pair(4, 0); __syncthreads();
    stXT2(ft, 0, 0);                 ph1pair(6, 1); __syncthreads();
    ywrite();  // wave-private; lgkmcnt auto-inserted before ph2 reads
    stXT2(ft, 1, 1);                 ph2half(0, 0); __syncthreads();
    if (ft < 7) stAT2(ft + 1, 0, 0); ph2half(8, 1); __syncthreads();
  }

  const float scale = 0.044194173824159216f;  // 1/sqrt(512)
#pragma unroll
  for (int th = 0; th < 2; ++th)
#pragma unroll
    for (int ct = 0; ct < 8; ++ct)
#pragma unroll
      for (int r = 0; r < 4; ++r) {
        const int row = w * 16 + lk * 4 + r;
        prodc[(size_t)row * 256 + th * 128 + ct * 16 + lr] =
            accz[th * 8 + ct][r] * scale;
      }
}

// ---------------- K3: cross-channel softmax -> bf16 sm in k4-tiled layout ----------
__launch_bounds__(512)
__global__ void k3_softmax(const float* __restrict__ prodf, unsigned short* __restrict__ smT) {
  const int bid = blockIdx.x;  // b*256 + s
  const int b = bid >> 8, s = bid & 255;
  const int tid = threadIdx.x;
  const int t = tid & 255, ch = tid >> 8;
  const float* __restrict__ p =
      prodf + (size_t)b * (512ull * 65536) + (size_t)s * 256 + t + (size_t)ch * 256 * 65536;
  float m = -3.4e38f, sum = 0.f;
#pragma unroll 4
  for (int cc = 0; cc < 256; ++cc) {
    const float v = p[(size_t)cc * 65536];
    if (v > m) { sum *= __expf(m - v); m = v; }
    sum += __expf(v - m);
  }
  __shared__ float Ms[2][256], Ss[2][256];
  Ms[ch][t] = m; Ss[ch][t] = sum;
  __syncthreads();
  const float mo = Ms[ch ^ 1][t], so = Ss[ch ^ 1][t];
  const float mm = fmaxf(m, mo);
  const float inv = 1.0f / (sum * __expf(m - mm) + so * __expf(mo - mm));
  const int sh = s >> 7, r = s & 127, kt = t >> 6, col = t & 63;
  const int cidx = r * 64 + ((col & 3) | ((col & 60) ^ ((r & 7) << 3)));
  const size_t tbase = ((size_t)b * 512 + ch * 256) * 2 + sh;
#pragma unroll 4
  for (int cc = 0; cc < 256; ++cc) {
    const float ev = __expf(p[(size_t)cc * 65536] - mm) * inv;
    smT[((tbase + (size_t)cc * 2) * 4 + kt) * 8192 + cidx] = f2bf(ev);
  }
}

// ---------------- K4: out = sm·v + xn  (bf16 MFMA; residual from XNh bf16) ----------
__launch_bounds__(256)
__global__ void k4_pv(const unsigned short* __restrict__ XNh_g,
                      const unsigned short* __restrict__ vT,
                      const unsigned short* __restrict__ smT,
                      float* __restrict__ out) {
  __shared__ unsigned short BUF[2][16384];  // each: [SM 8192][VT 8192] = 32 KiB
  const int bid = blockIdx.x;
  const int L = (bid & 7) * 1024 + (bid >> 3);  // chunked XCD swizzle
  const int bc = L >> 3;
  const int sh = (L >> 2) & 1;
  const int fh = L & 3;
  const int s0 = sh * 128, f0 = fh * 128;
  const int tid = threadIdx.x, w = tid >> 6, lane = tid & 63;

  f32x4 acc[2][8];
#pragma unroll
  for (int i = 0; i < 2; ++i)
#pragma unroll
    for (int j = 0; j < 8; ++j) acc[i][j] = (f32x4){0.f, 0.f, 0.f, 0.f};

  stage_tile(smT + (((size_t)bc * 2 + sh) * 4 + 0) * 8192, &BUF[0][0], 16384, w, lane, 4);
  stage_tile(vT + (((size_t)bc * 4 + fh) * 4 + 0) * 8192, &BUF[0][8192], 16384, w, lane, 4);
  __syncthreads();
#pragma unroll 1
  for (int kt = 0; kt < 4; ++kt) {
    if (kt < 3) {
      const int b = (kt + 1) & 1;
      stage_tile(smT + (((size_t)bc * 2 + sh) * 4 + kt + 1) * 8192, &BUF[b][0],
                 16384, w, lane, 4);
      stage_tile(vT + (((size_t)bc * 4 + fh) * 4 + kt + 1) * 8192, &BUF[b][8192],
                 16384, w, lane, 4);
    }
    const unsigned short* cb = &BUF[kt & 1][0];
#pragma unroll
    for (int ks = 0; ks < 2; ++ks) {
      bf16x8 a0 = ldfrag(cb, w * 32 + (lane & 15), ks, lane);
      bf16x8 a1 = ldfrag(cb, w * 32 + 16 + (lane & 15), ks, lane);
#pragma unroll
      for (int ct = 0; ct < 8; ++ct) {
        bf16x8 b = ldfrag(cb + 8192, ct * 16 + (lane & 15), ks, lane);
        acc[0][ct] = MFMA(a0, b, acc[0][ct]);
        acc[1][ct] = MFMA(a1, b, acc[1][ct]);
      }
    }
    __syncthreads();
  }
  const int lr = lane & 15, lk = lane >> 4;
#pragma unroll
  for (int rt = 0; rt < 2; ++rt)
#pragma unroll
    for (int ct = 0; ct < 8; ++ct)
#pragma unroll
      for (int r = 0; r < 4; ++r) {
        const int srow = s0 + w * 32 + rt * 16 + lk * 4 + r;
        const int fcol = f0 + ct * 16 + lr;
        const int et = fcol >> 6, col = fcol & 63;
        const unsigned short xh = XNh_g[((size_t)(bc * 8 + et) * 256 + srow) * 64 +
                                        ((col & 3) | ((col & 60) ^ ((srow & 7) << 3)))];
        const size_t oi = (size_t)bc * 131072 + (size_t)srow * 512 + fcol;
        out[oi] = acc[rt][ct][r] + bf2f(xh);
      }
}

extern "C" void kernel_launch(void* const* d_in, const int* in_sizes, int n_in,
                              void* d_out, int out_size, void* d_ws, size_t ws_size,
                              hipStream_t stream) {
  const float* x = (const float*)d_in[0];
  const float* Q = (const float*)d_in[1];
  const float* K = (const float*)d_in[2];
  const float* V = (const float*)d_in[3];
  float* out = (float*)d_out;
  float* ws = (float*)d_ws;
  float* prodf = (float*)((char*)d_ws + PROD_B);
  unsigned short* vT   = (unsigned short*)((char*)d_ws + V_B);
  unsigned short* ATh  = (unsigned short*)((char*)d_ws + ATH_B);
  unsigned short* ATl  = (unsigned short*)((char*)d_ws + ATL_B);
  unsigned short* VTm  = (unsigned short*)((char*)d_ws + VT_B);
  unsigned short* XNh  = (unsigned short*)((char*)d_ws + XNH_B);
  unsigned short* XNl  = (unsigned short*)((char*)d_ws + XNL_B);
  unsigned short* smT  = (unsigned short*)((char*)d_ws + SMT_B);
  if (ws_size < WS_BIG) {
    fprintf(stderr, "kernel_launch: ws_size %zu < needed %zu — expect corruption\n",
            ws_size, WS_BIG);
  }
  k1_stats<<<dim3(512), dim3(256), 0, stream>>>(x, ws);
  kA<<<dim3(512), dim3(256), 0, stream>>>(Q, K, V, ATh, ATl, VTm);
  kxn<<<dim3(2048), dim3(256), 0, stream>>>(x, ws, XNh, XNl);
  kv_proj<<<dim3(8192), dim3(256), 0, stream>>>(VTm, XNh, vT);
  kscores<<<dim3(2048), dim3(512), 0, stream>>>(ATh, ATl, XNh, XNl, prodf);
  k3_softmax<<<dim3(512), dim3(512), 0, stream>>>(prodf, smT);
  k4_pv<<<dim3(8192), dim3(256), 0, stream>>>(XNh, vT, smT, out);
}